// Round 1
// baseline (12.153 us; speedup 1.0000x reference)
//
#include <hip/hip_runtime.h>

// WaveletModel: out[b,k,n] = sum_j x[b, k%8, n + j - 1151] * wav[k%16, j]
//   wav[s,j] = (1 - j^2/sig^2) * exp(-j^2/(2 sig^2)),  sig = scales[s]/(2*pi)
// Key facts:
//  - output channel k depends only on k%16 (16 distinct convs, replicated 8x)
//  - wavelet decays to exact f32 zero beyond ~13*sigma (<= ~210 taps for scale=100)
//    -> truncate reduction at jmax = 12*sigma + 4 (residual terms <= e^-72, far
//       below the 0.27 absmax threshold)

#define NPIX 2304       // N = 48*48
#define NC 8
#define LEFT 1151       // (N-1)//2, 'same' padding left
#define TILE 1152       // n-tile per block (2 tiles cover NPIX)
#define THREADS 576     // 9 waves; each thread owns 2 contiguous outputs
#define JCAP 512        // max truncated kernel length we support (scale up to ~265)

__global__ __launch_bounds__(THREADS)
void wavelet_conv_kernel(const float* __restrict__ x,
                         const float* __restrict__ scales,
                         float* __restrict__ out) {
    __shared__ float ws[JCAP];
    __shared__ float xp[TILE + JCAP];

    const int bx   = blockIdx.x;      // [0, 256)
    const int pair = bx >> 1;         // [0, 128) = b*16 + d
    const int half = bx & 1;
    const int b    = pair >> 4;
    const int d    = pair & 15;       // distinct conv index (= k % 16)
    const int c    = d & 7;           // input channel (= k % 8)
    const int t0   = half * TILE;
    const int tid  = threadIdx.x;

    const float scale  = scales[d];
    const float sigma  = scale * 0.15915494309189535f;   // scale / (2*pi)
    const float inv_s2 = 1.0f / (sigma * sigma);
    int jmax = (int)(12.0f * sigma) + 4;                 // exp(-72) tail cut
    if (jmax > NPIX) jmax = NPIX;
    if (jmax > JCAP) jmax = JCAP;

    // stage truncated wavelet row
    for (int i = tid; i < jmax; i += THREADS) {
        float fj = (float)i;
        float a  = fj * fj * inv_s2;                     // t^2 / sigma^2
        ws[i] = (1.0f - a) * __expf(-0.5f * a);
    }
    // stage zero-padded x window: xp[i] = x[t0 - LEFT + i]
    const float* xrow = x + (size_t)(b * NC + c) * NPIX;
    const int xlen = TILE + jmax;
    for (int i = tid; i < xlen; i += THREADS) {
        int g = t0 - LEFT + i;
        xp[i] = (g >= 0 && g < NPIX) ? xrow[g] : 0.0f;
    }
    __syncthreads();

    // thread t computes outputs n0 = t0 + 2t, n0+1 with a sliding x register:
    // per tap: 1 LDS x-read (stride-2 lanes = free 2-way), 1 broadcast w-read, 2 FMA
    const int base = 2 * tid;
    float acc0 = 0.0f, acc1 = 0.0f;
    float xc = xp[base];
    #pragma unroll 4
    for (int j = 0; j < jmax; ++j) {
        float wv = ws[j];
        float xn = xp[base + j + 1];
        acc0 = fmaf(xc, wv, acc0);
        acc1 = fmaf(xn, wv, acc1);
        xc = xn;
    }

    // replicate to all 8 duplicate channels k = d + 16*kk (coalesced float2)
    const int n0 = t0 + base;
    float2 v = make_float2(acc0, acc1);
    #pragma unroll
    for (int kk = 0; kk < 8; ++kk) {
        int k = d + 16 * kk;
        *reinterpret_cast<float2*>(out + (size_t)(b * 128 + k) * NPIX + n0) = v;
    }
}

extern "C" void kernel_launch(void* const* d_in, const int* in_sizes, int n_in,
                              void* d_out, int out_size, void* d_ws, size_t ws_size,
                              hipStream_t stream) {
    const float* x      = (const float*)d_in[0];
    const float* scales = (const float*)d_in[1];
    float* out          = (float*)d_out;
    wavelet_conv_kernel<<<256, THREADS, 0, stream>>>(x, scales, out);
}